// Round 1
// 1085.446 us; speedup vs baseline: 1.0739x; 1.0739x over previous
//
#include <hip/hip_runtime.h>
#include <hip/hip_bf16.h>

#define N_NODES 50000
#define N_EDGES 600000
#define DD 128
#define EPS 1e-6f

#define NBLK_SCAN 196              // ceil(50000/256)
#define CNT_LEN   (NBLK_SCAN*256)  // 50176, padded

typedef __bf16 bf16;
typedef __attribute__((ext_vector_type(8))) __bf16 bf16x8;
typedef __attribute__((ext_vector_type(4))) float f32x4;

__device__ __forceinline__ f32x4 mfma16(bf16x8 a, bf16x8 b, f32x4 c) {
    return __builtin_amdgcn_mfma_f32_16x16x32_bf16(a, b, c, 0, 0, 0);
}

__device__ __forceinline__ int wave_incl_scan(int v, int lane) {
#pragma unroll
    for (int ofs = 1; ofs < 64; ofs <<= 1) {
        int t = __shfl_up(v, ofs, 64);
        if (lane >= ofs) v += t;
    }
    return v;
}

// ---------------- W f32 -> bf16 conversion (5 matrices of 128x128) ----------------
__global__ void conv_w_kernel(const float* __restrict__ WA, const float* __restrict__ WB,
                              const float* __restrict__ WC, const float* __restrict__ WD,
                              const float* __restrict__ WE, bf16* __restrict__ out) {
    int i = blockIdx.x * 256 + threadIdx.x;   // 0 .. 81919
    const float* srcs[5] = {WA, WB, WC, WD, WE};
    int w = i >> 14;          // /16384
    int j = i & 16383;
    out[i] = (bf16)srcs[w][j];
}

// ---------------- counting sort of edges by dst ------------------------------------
__global__ void hist_kernel(const int* __restrict__ dst, int* __restrict__ cnt) {
    int i = blockIdx.x * 256 + threadIdx.x;
    if (i < N_EDGES) atomicAdd(&cnt[dst[i]], 1);
}

__global__ __launch_bounds__(256) void scan_a_kernel(const int* __restrict__ cnt,
                                                     int* __restrict__ dpos,
                                                     int* __restrict__ bsum) {
    __shared__ int wsum[4];
    int tid = threadIdx.x, lane = tid & 63, wv = tid >> 6;
    int i = blockIdx.x * 256 + tid;
    int v = (i < N_NODES) ? cnt[i] : 0;
    int s = wave_incl_scan(v, lane);
    if (lane == 63) wsum[wv] = s;
    __syncthreads();
    int woff = 0;
#pragma unroll
    for (int w = 0; w < 3; ++w) if (w < wv) woff += wsum[w];
    if (i < N_NODES) dpos[i] = woff + s - v;      // block-local exclusive
    if (tid == 255) bsum[blockIdx.x] = woff + s;  // block total
}

__global__ __launch_bounds__(256) void scan_b_kernel(int* __restrict__ bsum) {
    __shared__ int wsum[4];
    int tid = threadIdx.x, lane = tid & 63, wv = tid >> 6;
    int v = (tid < NBLK_SCAN) ? bsum[tid] : 0;
    int s = wave_incl_scan(v, lane);
    if (lane == 63) wsum[wv] = s;
    __syncthreads();
    int woff = 0;
#pragma unroll
    for (int w = 0; w < 3; ++w) if (w < wv) woff += wsum[w];
    if (tid < NBLK_SCAN) bsum[tid] = woff + s - v;   // exclusive block offsets
}

__global__ void scan_c_kernel(int* __restrict__ dpos, const int* __restrict__ bsum) {
    int i = blockIdx.x * 256 + threadIdx.x;
    if (i < N_NODES) dpos[i] += bsum[blockIdx.x];
}

__global__ void scatter_kernel(const int* __restrict__ dst, int* __restrict__ dpos,
                               int* __restrict__ perm) {
    int i = blockIdx.x * 256 + threadIdx.x;
    if (i < N_EDGES) {
        int p = atomicAdd(&dpos[dst[i]], 1);
        perm[p] = i;
    }
}

// ---------------- node GEMMs: Ah,Bh,Dh,Eh = h @ W.T + b  (stored bf16) -------------
__global__ __launch_bounds__(256) void node_gemm_kernel(
    const float* __restrict__ h, const bf16* __restrict__ Wb,
    const float* __restrict__ bA, const float* __restrict__ bB,
    const float* __restrict__ bD, const float* __restrict__ bE,
    bf16* __restrict__ Ah, bf16* __restrict__ Bh,
    bf16* __restrict__ Dh, bf16* __restrict__ Eh)
{
    __shared__ bf16 hs[64 * 136];   // stride 136 bf16 (272B): 2-way LDS aliasing only
    int tid = threadIdx.x;
    int n0 = blockIdx.x * 64;

#pragma unroll
    for (int it = 0; it < 8; ++it) {
        int idx = it * 256 + tid;       // 2048 float4 chunks
        int row = idx >> 5;             // 32 chunks per row
        int c4  = idx & 31;
        int grow = n0 + row;
        if (grow >= N_NODES) grow = N_NODES - 1;  // clamp: garbage rows never stored
        float4 v = ((const float4*)h)[grow * 32 + c4];
        bf16* d = &hs[row * 136 + c4 * 4];
        d[0] = (bf16)v.x; d[1] = (bf16)v.y; d[2] = (bf16)v.z; d[3] = (bf16)v.w;
    }
    __syncthreads();

    int lane = tid & 63, wv = tid >> 6;
    int l15 = lane & 15, quad = lane >> 4;

    const bf16* Wsel[4] = {Wb, Wb + 16384, Wb + 3 * 16384, Wb + 4 * 16384}; // A,B,D,E
    const float* bsel[4] = {bA, bB, bD, bE};
    bf16* osel[4] = {Ah, Bh, Dh, Eh};

#pragma unroll 1
    for (int wi = 0; wi < 4; ++wi) {
        const bf16* W = Wsel[wi];
        f32x4 acc[4][2] = {};
#pragma unroll
        for (int ks = 0; ks < 4; ++ks) {
            int kk = ks * 32 + quad * 8;
            bf16x8 b0 = *(const bf16x8*)&W[((2 * wv) * 16 + l15) * 128 + kk];
            bf16x8 b1 = *(const bf16x8*)&W[((2 * wv + 1) * 16 + l15) * 128 + kk];
#pragma unroll
            for (int mt = 0; mt < 4; ++mt) {
                bf16x8 a = *(const bf16x8*)&hs[(mt * 16 + l15) * 136 + kk];
                acc[mt][0] = mfma16(a, b0, acc[mt][0]);
                acc[mt][1] = mfma16(a, b1, acc[mt][1]);
            }
        }
#pragma unroll
        for (int nt = 0; nt < 2; ++nt) {
            int col = (2 * wv + nt) * 16 + l15;
            float bias = bsel[wi][col];
#pragma unroll
            for (int mt = 0; mt < 4; ++mt) {
#pragma unroll
                for (int r = 0; r < 4; ++r) {
                    int row = mt * 16 + quad * 4 + r;
                    int grow = n0 + row;
                    if (grow < N_NODES)
                        osel[wi][grow * 128 + col] = (bf16)(acc[mt][nt][r] + bias);
                }
            }
        }
    }
}

// ---------------- edge kernel (dst-sorted): Ce GEMM + gather + gate + atomics ------
// block = 256 threads, 64 edges per block, edges taken via perm (sorted by dst).
__global__ __launch_bounds__(256) void edge_kernel(
    const float* __restrict__ e, const int* __restrict__ src, const int* __restrict__ dst,
    const int* __restrict__ perm,
    const bf16* __restrict__ WCb, const float* __restrict__ bC,
    const bf16* __restrict__ Bh, const bf16* __restrict__ Dh, const bf16* __restrict__ Eh,
    float* __restrict__ sum_sigma, float* __restrict__ sum_msg,
    float* __restrict__ e_out)
{
    __shared__ bf16 es[64 * 136];
    __shared__ int s_ei[64];
    __shared__ int s_src[64];
    __shared__ int s_dst[64];
    int tid = threadIdx.x;
    int e0 = blockIdx.x * 64;

    if (tid < 64) {
        int p = perm[e0 + tid];
        s_ei[tid]  = p;
        s_src[tid] = src[p];
        s_dst[tid] = dst[p];
    }
    __syncthreads();

#pragma unroll
    for (int it = 0; it < 8; ++it) {
        int idx = it * 256 + tid;
        int row = idx >> 5;
        int c4  = idx & 31;
        float4 v = ((const float4*)e)[s_ei[row] * 32 + c4];
        bf16* d = &es[row * 136 + c4 * 4];
        d[0] = (bf16)v.x; d[1] = (bf16)v.y; d[2] = (bf16)v.z; d[3] = (bf16)v.w;
    }
    __syncthreads();

    int lane = tid & 63, wv = tid >> 6;
    int l15 = lane & 15, quad = lane >> 4;

    f32x4 acc[4][2] = {};
#pragma unroll
    for (int ks = 0; ks < 4; ++ks) {
        int kk = ks * 32 + quad * 8;
        bf16x8 b0 = *(const bf16x8*)&WCb[((2 * wv) * 16 + l15) * 128 + kk];
        bf16x8 b1 = *(const bf16x8*)&WCb[((2 * wv + 1) * 16 + l15) * 128 + kk];
#pragma unroll
        for (int mt = 0; mt < 4; ++mt) {
            bf16x8 a = *(const bf16x8*)&es[(mt * 16 + l15) * 136 + kk];
            acc[mt][0] = mfma16(a, b0, acc[mt][0]);
            acc[mt][1] = mfma16(a, b1, acc[mt][1]);
        }
    }

#pragma unroll
    for (int nt = 0; nt < 2; ++nt) {
        int col = (2 * wv + nt) * 16 + l15;
        float bc = bC[col];
#pragma unroll
        for (int mt = 0; mt < 4; ++mt) {
            // rows mt*16 + quad*4 + r (r=0..3) are 4 CONSECUTIVE sorted edges:
            // run-compress atomics while dst is unchanged.
            float a_sg = 0.f, a_ms = 0.f;
            int prev = -1;
#pragma unroll
            for (int r = 0; r < 4; ++r) {
                int row = mt * 16 + quad * 4 + r;
                int ei = s_ei[row];
                int s  = s_src[row];
                int dd = s_dst[row];
                float dh = (float)Dh[s * 128 + col];
                float eh = (float)Eh[dd * 128 + col];
                float bh = (float)Bh[s * 128 + col];
                float enew = acc[mt][nt][r] + bc + dh + eh;
                float sg = 1.0f / (1.0f + __expf(-enew));
                float ein = e[(size_t)ei * 128 + col];
                e_out[(size_t)ei * 128 + col] = ein + enew * sg;   // e + silu(e_new)
                if (dd != prev && prev >= 0) {
                    unsafeAtomicAdd(&sum_sigma[prev * 128 + col], a_sg);
                    unsafeAtomicAdd(&sum_msg[prev * 128 + col], a_ms);
                    a_sg = 0.f; a_ms = 0.f;
                }
                a_sg += sg;
                a_ms += bh * sg;
                prev = dd;
            }
            unsafeAtomicAdd(&sum_sigma[prev * 128 + col], a_sg);
            unsafeAtomicAdd(&sum_msg[prev * 128 + col], a_ms);
        }
    }
}

// ---------------- node finalize: h_out = h + silu(Ah + sum_msg/(sum_sigma+eps)) ----
__global__ void node_final_kernel(const float* __restrict__ h, const bf16* __restrict__ Ah,
                                  const float* __restrict__ sum_sigma,
                                  const float* __restrict__ sum_msg,
                                  float* __restrict__ h_out)
{
    int i = blockIdx.x * 256 + threadIdx.x;
    if (i < N_NODES * DD) {
        float hn = (float)Ah[i] + sum_msg[i] / (sum_sigma[i] + EPS);
        float sg = 1.0f / (1.0f + __expf(-hn));
        h_out[i] = h[i] + hn * sg;
    }
}

extern "C" void kernel_launch(void* const* d_in, const int* in_sizes, int n_in,
                              void* d_out, int out_size, void* d_ws, size_t ws_size,
                              hipStream_t stream) {
    const float* h   = (const float*)d_in[0];
    const float* e   = (const float*)d_in[1];
    const int*   src = (const int*)d_in[2];
    const int*   dst = (const int*)d_in[3];
    const float* WA = (const float*)d_in[4];  const float* bA = (const float*)d_in[5];
    const float* WB = (const float*)d_in[6];  const float* bB = (const float*)d_in[7];
    const float* WC = (const float*)d_in[8];  const float* bC = (const float*)d_in[9];
    const float* WD = (const float*)d_in[10]; const float* bD = (const float*)d_in[11];
    const float* WE = (const float*)d_in[12]; const float* bE = (const float*)d_in[13];

    float* h_out = (float*)d_out;
    float* e_out = h_out + (size_t)N_NODES * DD;

    char* ws = (char*)d_ws;
    bf16* Wb = (bf16*)ws;            ws += (size_t)5 * 16384 * sizeof(bf16);
    bf16* Ah = (bf16*)ws;            ws += (size_t)N_NODES * DD * sizeof(bf16);
    bf16* Bh = (bf16*)ws;            ws += (size_t)N_NODES * DD * sizeof(bf16);
    bf16* Dh = (bf16*)ws;            ws += (size_t)N_NODES * DD * sizeof(bf16);
    bf16* Eh = (bf16*)ws;            ws += (size_t)N_NODES * DD * sizeof(bf16);
    float* sum_sigma = (float*)ws;   ws += (size_t)N_NODES * DD * sizeof(float);
    float* sum_msg   = (float*)ws;   ws += (size_t)N_NODES * DD * sizeof(float);
    int* counts = (int*)ws;          ws += (size_t)CNT_LEN * sizeof(int);
    int* dpos   = (int*)ws;          ws += (size_t)CNT_LEN * sizeof(int);
    int* bsum   = (int*)ws;          ws += (size_t)256 * sizeof(int);
    int* perm   = (int*)ws;          ws += (size_t)N_EDGES * sizeof(int);

    // zero: sum_sigma, sum_msg, counts (contiguous)
    hipMemsetAsync(sum_sigma, 0,
                   (size_t)2 * N_NODES * DD * sizeof(float) + (size_t)CNT_LEN * sizeof(int),
                   stream);

    conv_w_kernel<<<320, 256, 0, stream>>>(WA, WB, WC, WD, WE, Wb);

    // counting sort of edge ids by dst
    hist_kernel<<<(N_EDGES + 255) / 256, 256, 0, stream>>>(dst, counts);
    scan_a_kernel<<<NBLK_SCAN, 256, 0, stream>>>(counts, dpos, bsum);
    scan_b_kernel<<<1, 256, 0, stream>>>(bsum);
    scan_c_kernel<<<NBLK_SCAN, 256, 0, stream>>>(dpos, bsum);
    scatter_kernel<<<(N_EDGES + 255) / 256, 256, 0, stream>>>(dst, dpos, perm);

    node_gemm_kernel<<<(N_NODES + 63) / 64, 256, 0, stream>>>(
        h, Wb, bA, bB, bD, bE, Ah, Bh, Dh, Eh);
    edge_kernel<<<N_EDGES / 64, 256, 0, stream>>>(
        e, src, dst, perm, Wb + 2 * 16384, bC, Bh, Dh, Eh, sum_sigma, sum_msg, e_out);
    node_final_kernel<<<(N_NODES * DD + 255) / 256, 256, 0, stream>>>(
        h, Ah, sum_sigma, sum_msg, h_out);
}

// Round 2
// 873.414 us; speedup vs baseline: 1.3346x; 1.2428x over previous
//
#include <hip/hip_runtime.h>
#include <hip/hip_bf16.h>

#define N_NODES 50000
#define N_EDGES 600000
#define DD 128
#define EPS 1e-6f

#define NBLK_SCAN 196              // ceil(50000/256)
#define CNT_LEN   (NBLK_SCAN*256)  // 50176, padded

typedef __bf16 bf16;
typedef __attribute__((ext_vector_type(8))) __bf16 bf16x8;
typedef __attribute__((ext_vector_type(4))) __bf16 bf16x4;
typedef __attribute__((ext_vector_type(4))) float f32x4;

__device__ __forceinline__ f32x4 mfma16(bf16x8 a, bf16x8 b, f32x4 c) {
    return __builtin_amdgcn_mfma_f32_16x16x32_bf16(a, b, c, 0, 0, 0);
}

__device__ __forceinline__ int wave_incl_scan(int v, int lane) {
#pragma unroll
    for (int ofs = 1; ofs < 64; ofs <<= 1) {
        int t = __shfl_up(v, ofs, 64);
        if (lane >= ofs) v += t;
    }
    return v;
}

// ---------------- W f32 -> bf16 conversion (5 matrices of 128x128) ----------------
__global__ void conv_w_kernel(const float* __restrict__ WA, const float* __restrict__ WB,
                              const float* __restrict__ WC, const float* __restrict__ WD,
                              const float* __restrict__ WE, bf16* __restrict__ out) {
    int i = blockIdx.x * 256 + threadIdx.x;   // 0 .. 81919
    int w = i >> 14;          // /16384
    int j = i & 16383;
    const float* s;
    if (w == 0) s = WA; else if (w == 1) s = WB; else if (w == 2) s = WC;
    else if (w == 3) s = WD; else s = WE;
    out[i] = (bf16)s[j];
}

// ---------------- counting sort of edges by dst ------------------------------------
__global__ void hist_kernel(const int* __restrict__ dst, int* __restrict__ cnt) {
    int i = blockIdx.x * 256 + threadIdx.x;
    if (i < N_EDGES) atomicAdd(&cnt[dst[i]], 1);
}

__global__ __launch_bounds__(256) void scan_a_kernel(const int* __restrict__ cnt,
                                                     int* __restrict__ dpos,
                                                     int* __restrict__ bsum) {
    __shared__ int wsum[4];
    int tid = threadIdx.x, lane = tid & 63, wv = tid >> 6;
    int i = blockIdx.x * 256 + tid;
    int v = (i < N_NODES) ? cnt[i] : 0;
    int s = wave_incl_scan(v, lane);
    if (lane == 63) wsum[wv] = s;
    __syncthreads();
    int woff = 0;
#pragma unroll
    for (int w = 0; w < 3; ++w) if (w < wv) woff += wsum[w];
    if (i < N_NODES) dpos[i] = woff + s - v;      // block-local exclusive
    if (tid == 255) bsum[blockIdx.x] = woff + s;  // block total
}

__global__ __launch_bounds__(256) void scan_b_kernel(int* __restrict__ bsum) {
    __shared__ int wsum[4];
    int tid = threadIdx.x, lane = tid & 63, wv = tid >> 6;
    int v = (tid < NBLK_SCAN) ? bsum[tid] : 0;
    int s = wave_incl_scan(v, lane);
    if (lane == 63) wsum[wv] = s;
    __syncthreads();
    int woff = 0;
#pragma unroll
    for (int w = 0; w < 3; ++w) if (w < wv) woff += wsum[w];
    if (tid < NBLK_SCAN) bsum[tid] = woff + s - v;   // exclusive block offsets
}

__global__ void scan_c_kernel(int* __restrict__ dpos, const int* __restrict__ bsum,
                              int* __restrict__ spos) {
    int i = blockIdx.x * 256 + threadIdx.x;
    if (i < N_NODES) {
        int v = dpos[i] + bsum[blockIdx.x];
        dpos[i] = v;     // CSR row start (preserved for node_agg)
        spos[i] = v;     // scatter cursor (consumed by scatter_kernel)
    }
}

// scatter: for each edge, record its dst-sorted position (inv) and src at that slot
__global__ void scatter_kernel(const int* __restrict__ src, const int* __restrict__ dst,
                               int* __restrict__ spos,
                               int* __restrict__ srcs_sorted, int* __restrict__ inv) {
    int i = blockIdx.x * 256 + threadIdx.x;
    if (i < N_EDGES) {
        int p = atomicAdd(&spos[dst[i]], 1);
        srcs_sorted[p] = src[i];
        inv[i] = p;
    }
}

// ---------------- node GEMMs: Ah,Bh,Dh,Eh = h @ W.T + b  (stored bf16) -------------
__global__ __launch_bounds__(256) void node_gemm_kernel(
    const float* __restrict__ h, const bf16* __restrict__ Wb,
    const float* __restrict__ bA, const float* __restrict__ bB,
    const float* __restrict__ bD, const float* __restrict__ bE,
    bf16* __restrict__ Ah, bf16* __restrict__ Bh,
    bf16* __restrict__ Dh, bf16* __restrict__ Eh)
{
    __shared__ bf16 hs[64 * 136];   // stride 136 bf16 (272B): 2-way LDS aliasing only
    int tid = threadIdx.x;
    int n0 = blockIdx.x * 64;

#pragma unroll
    for (int it = 0; it < 8; ++it) {
        int idx = it * 256 + tid;       // 2048 float4 chunks
        int row = idx >> 5;             // 32 chunks per row
        int c4  = idx & 31;
        int grow = n0 + row;
        if (grow >= N_NODES) grow = N_NODES - 1;  // clamp: garbage rows never stored
        float4 v = ((const float4*)h)[grow * 32 + c4];
        bf16x4 p; p[0] = (bf16)v.x; p[1] = (bf16)v.y; p[2] = (bf16)v.z; p[3] = (bf16)v.w;
        *(bf16x4*)&hs[row * 136 + c4 * 4] = p;
    }
    __syncthreads();

    int lane = tid & 63, wv = tid >> 6;
    int l15 = lane & 15, quad = lane >> 4;

#pragma unroll 1
    for (int wi = 0; wi < 4; ++wi) {
        const bf16* W; const float* bias; bf16* out;
        if (wi == 0)      { W = Wb;             bias = bA; out = Ah; }
        else if (wi == 1) { W = Wb + 16384;     bias = bB; out = Bh; }
        else if (wi == 2) { W = Wb + 3 * 16384; bias = bD; out = Dh; }
        else              { W = Wb + 4 * 16384; bias = bE; out = Eh; }
        f32x4 acc[4][2] = {};
#pragma unroll
        for (int ks = 0; ks < 4; ++ks) {
            int kk = ks * 32 + quad * 8;
            bf16x8 b0 = *(const bf16x8*)&W[((2 * wv) * 16 + l15) * 128 + kk];
            bf16x8 b1 = *(const bf16x8*)&W[((2 * wv + 1) * 16 + l15) * 128 + kk];
#pragma unroll
            for (int mt = 0; mt < 4; ++mt) {
                bf16x8 a = *(const bf16x8*)&hs[(mt * 16 + l15) * 136 + kk];
                acc[mt][0] = mfma16(a, b0, acc[mt][0]);
                acc[mt][1] = mfma16(a, b1, acc[mt][1]);
            }
        }
#pragma unroll
        for (int nt = 0; nt < 2; ++nt) {
            int col = (2 * wv + nt) * 16 + l15;
            float bias_v = bias[col];
#pragma unroll
            for (int mt = 0; mt < 4; ++mt) {
#pragma unroll
                for (int r = 0; r < 4; ++r) {
                    int row = mt * 16 + quad * 4 + r;
                    int grow = n0 + row;
                    if (grow < N_NODES)
                        out[grow * 128 + col] = (bf16)(acc[mt][nt][r] + bias_v);
                }
            }
        }
    }
}

// ---------------- edge kernel (NATURAL order): Ce GEMM + gather + gate -------------
// Streams e sequentially; writes e_out sequentially; writes sigma (bf16) into
// dst-sorted position (full 256B rows). No atomics.
__global__ __launch_bounds__(256) void edge_kernel(
    const float* __restrict__ e, const int* __restrict__ src, const int* __restrict__ dst,
    const int* __restrict__ inv,
    const bf16* __restrict__ WCb, const float* __restrict__ bC,
    const bf16* __restrict__ Dh, const bf16* __restrict__ Eh,
    bf16* __restrict__ sgb, float* __restrict__ e_out)
{
    __shared__ bf16 es[64 * 136];
    __shared__ int s_src[64];
    __shared__ int s_dst[64];
    __shared__ int s_pos[64];
    int tid = threadIdx.x;
    int e0 = blockIdx.x * 64;

    if (tid < 64)        s_src[tid]       = src[e0 + tid];
    else if (tid < 128)  s_dst[tid - 64]  = dst[e0 + tid - 64];
    else if (tid < 192)  s_pos[tid - 128] = inv[e0 + tid - 128];

#pragma unroll
    for (int it = 0; it < 8; ++it) {
        int idx = it * 256 + tid;
        int row = idx >> 5;
        int c4  = idx & 31;
        float4 v = ((const float4*)e)[(e0 + row) * 32 + c4];
        bf16x4 p; p[0] = (bf16)v.x; p[1] = (bf16)v.y; p[2] = (bf16)v.z; p[3] = (bf16)v.w;
        *(bf16x4*)&es[row * 136 + c4 * 4] = p;
    }
    __syncthreads();

    int lane = tid & 63, wv = tid >> 6;
    int l15 = lane & 15, quad = lane >> 4;

    f32x4 acc[4][2] = {};
#pragma unroll
    for (int ks = 0; ks < 4; ++ks) {
        int kk = ks * 32 + quad * 8;
        bf16x8 b0 = *(const bf16x8*)&WCb[((2 * wv) * 16 + l15) * 128 + kk];
        bf16x8 b1 = *(const bf16x8*)&WCb[((2 * wv + 1) * 16 + l15) * 128 + kk];
#pragma unroll
        for (int mt = 0; mt < 4; ++mt) {
            bf16x8 a = *(const bf16x8*)&es[(mt * 16 + l15) * 136 + kk];
            acc[mt][0] = mfma16(a, b0, acc[mt][0]);
            acc[mt][1] = mfma16(a, b1, acc[mt][1]);
        }
    }

#pragma unroll
    for (int nt = 0; nt < 2; ++nt) {
        int col = (2 * wv + nt) * 16 + l15;
        float bc = bC[col];
#pragma unroll
        for (int mt = 0; mt < 4; ++mt) {
#pragma unroll
            for (int r = 0; r < 4; ++r) {
                int row = mt * 16 + quad * 4 + r;
                int ei = e0 + row;
                int s  = s_src[row];
                int dd = s_dst[row];
                int ps = s_pos[row];
                float dh = (float)Dh[s * 128 + col];
                float eh = (float)Eh[dd * 128 + col];
                float enew = acc[mt][nt][r] + bc + dh + eh;
                float sg = 1.0f / (1.0f + __expf(-enew));
                float ein = e[(size_t)ei * 128 + col];          // L2 hit (just staged)
                e_out[(size_t)ei * 128 + col] = ein + enew * sg; // e + silu(e_new)
                sgb[(size_t)ps * 128 + col] = (bf16)sg;          // dst-sorted position
            }
        }
    }
}

// ---------------- node aggregation + finalize --------------------------------------
// sigma rows are CONTIGUOUS per node (dst-sorted). 16 lanes per node, 8 cols/lane.
// h_out = h + silu(Ah + sum(bh*sg)/(sum(sg)+eps))
__global__ __launch_bounds__(256) void node_agg_kernel(
    const int* __restrict__ rstart, const int* __restrict__ cnt,
    const int* __restrict__ srcs_sorted,
    const bf16* __restrict__ sgb, const bf16* __restrict__ Bh,
    const bf16* __restrict__ Ah, const float* __restrict__ h,
    float* __restrict__ h_out)
{
    int tid = threadIdx.x;
    int g = tid >> 4, c = tid & 15;
    int n = blockIdx.x * 16 + g;            // 3125 * 16 = 50000 exact

    int beg = rstart[n];
    int deg = cnt[n];

    float ssg[8] = {0.f, 0.f, 0.f, 0.f, 0.f, 0.f, 0.f, 0.f};
    float sms[8] = {0.f, 0.f, 0.f, 0.f, 0.f, 0.f, 0.f, 0.f};

    int j = 0;
    for (; j + 1 < deg; j += 2) {
        int s0 = srcs_sorted[beg + j];
        int s1 = srcs_sorted[beg + j + 1];
        bf16x8 g0 = *(const bf16x8*)&sgb[(size_t)(beg + j) * 128 + c * 8];
        bf16x8 g1 = *(const bf16x8*)&sgb[(size_t)(beg + j + 1) * 128 + c * 8];
        bf16x8 b0 = *(const bf16x8*)&Bh[(size_t)s0 * 128 + c * 8];
        bf16x8 b1 = *(const bf16x8*)&Bh[(size_t)s1 * 128 + c * 8];
#pragma unroll
        for (int k = 0; k < 8; ++k) {
            float v0 = (float)g0[k], v1 = (float)g1[k];
            ssg[k] += v0 + v1;
            sms[k] += v0 * (float)b0[k] + v1 * (float)b1[k];
        }
    }
    if (j < deg) {
        int s0 = srcs_sorted[beg + j];
        bf16x8 g0 = *(const bf16x8*)&sgb[(size_t)(beg + j) * 128 + c * 8];
        bf16x8 b0 = *(const bf16x8*)&Bh[(size_t)s0 * 128 + c * 8];
#pragma unroll
        for (int k = 0; k < 8; ++k) {
            float v0 = (float)g0[k];
            ssg[k] += v0;
            sms[k] += v0 * (float)b0[k];
        }
    }

    bf16x8 a8 = *(const bf16x8*)&Ah[(size_t)n * 128 + c * 8];
    const float4* h4 = (const float4*)h;
    float4 hv0 = h4[n * 32 + c * 2];
    float4 hv1 = h4[n * 32 + c * 2 + 1];

    float o[8];
#pragma unroll
    for (int k = 0; k < 8; ++k) {
        float hn = (float)a8[k] + sms[k] / (ssg[k] + EPS);
        float sig = 1.0f / (1.0f + __expf(-hn));
        o[k] = hn * sig;
    }
    float4 r0, r1;
    r0.x = hv0.x + o[0]; r0.y = hv0.y + o[1]; r0.z = hv0.z + o[2]; r0.w = hv0.w + o[3];
    r1.x = hv1.x + o[4]; r1.y = hv1.y + o[5]; r1.z = hv1.z + o[6]; r1.w = hv1.w + o[7];
    float4* o4 = (float4*)h_out;
    o4[n * 32 + c * 2]     = r0;
    o4[n * 32 + c * 2 + 1] = r1;
}

extern "C" void kernel_launch(void* const* d_in, const int* in_sizes, int n_in,
                              void* d_out, int out_size, void* d_ws, size_t ws_size,
                              hipStream_t stream) {
    const float* h   = (const float*)d_in[0];
    const float* e   = (const float*)d_in[1];
    const int*   src = (const int*)d_in[2];
    const int*   dst = (const int*)d_in[3];
    const float* WA = (const float*)d_in[4];  const float* bA = (const float*)d_in[5];
    const float* WB = (const float*)d_in[6];  const float* bB = (const float*)d_in[7];
    const float* WC = (const float*)d_in[8];  const float* bC = (const float*)d_in[9];
    const float* WD = (const float*)d_in[10]; const float* bD = (const float*)d_in[11];
    const float* WE = (const float*)d_in[12]; const float* bE = (const float*)d_in[13];

    float* h_out = (float*)d_out;
    float* e_out = h_out + (size_t)N_NODES * DD;

    char* ws = (char*)d_ws;
    bf16* Wb = (bf16*)ws;            ws += (size_t)5 * 16384 * sizeof(bf16);
    bf16* Ah = (bf16*)ws;            ws += (size_t)N_NODES * DD * sizeof(bf16);
    bf16* Bh = (bf16*)ws;            ws += (size_t)N_NODES * DD * sizeof(bf16);
    bf16* Dh = (bf16*)ws;            ws += (size_t)N_NODES * DD * sizeof(bf16);
    bf16* Eh = (bf16*)ws;            ws += (size_t)N_NODES * DD * sizeof(bf16);
    bf16* sgb = (bf16*)ws;           ws += (size_t)N_EDGES * DD * sizeof(bf16);   // 153.6 MB
    int* counts = (int*)ws;          ws += (size_t)CNT_LEN * sizeof(int);
    int* dpos   = (int*)ws;          ws += (size_t)CNT_LEN * sizeof(int);
    int* spos   = (int*)ws;          ws += (size_t)CNT_LEN * sizeof(int);
    int* bsum   = (int*)ws;          ws += (size_t)256 * sizeof(int);
    int* srcs_sorted = (int*)ws;     ws += (size_t)N_EDGES * sizeof(int);
    int* inv    = (int*)ws;          ws += (size_t)N_EDGES * sizeof(int);

    hipMemsetAsync(counts, 0, (size_t)CNT_LEN * sizeof(int), stream);

    conv_w_kernel<<<320, 256, 0, stream>>>(WA, WB, WC, WD, WE, Wb);

    // counting sort of edges by dst -> inv (edge -> sorted pos), srcs_sorted
    hist_kernel<<<(N_EDGES + 255) / 256, 256, 0, stream>>>(dst, counts);
    scan_a_kernel<<<NBLK_SCAN, 256, 0, stream>>>(counts, dpos, bsum);
    scan_b_kernel<<<1, 256, 0, stream>>>(bsum);
    scan_c_kernel<<<NBLK_SCAN, 256, 0, stream>>>(dpos, bsum, spos);
    scatter_kernel<<<(N_EDGES + 255) / 256, 256, 0, stream>>>(src, dst, spos, srcs_sorted, inv);

    node_gemm_kernel<<<(N_NODES + 63) / 64, 256, 0, stream>>>(
        h, Wb, bA, bB, bD, bE, Ah, Bh, Dh, Eh);
    edge_kernel<<<N_EDGES / 64, 256, 0, stream>>>(
        e, src, dst, inv, Wb + 2 * 16384, bC, Dh, Eh, sgb, e_out);
    node_agg_kernel<<<N_NODES / 16, 256, 0, stream>>>(
        dpos, counts, srcs_sorted, sgb, Bh, Ah, h, h_out);
}